// Round 1
// 4278.783 us; speedup vs baseline: 1.5984x; 1.5984x over previous
//
#include <hip/hip_runtime.h>

#define B_   2
#define NS   4
#define T_   2048
#define D_   1024
#define E_   16
#define ND   4096
#define DFFN 1656
#define BT   4096
#define TD   (T_*D_)
#define RCAP 16384
#define KSPLIT 8
#define EPS_ 1.1920929e-7f

typedef __bf16 bf16x8 __attribute__((ext_vector_type(8)));
typedef float  f32x4  __attribute__((ext_vector_type(4)));

static __device__ __forceinline__ float sigm(float x){ return 1.0f/(1.0f+__expf(-x)); }
static __device__ __forceinline__ unsigned short f2us(float x){
    return __builtin_bit_cast(unsigned short, (__bf16)x);
}
static __device__ __forceinline__ float us2f(unsigned short u){
    return (float)__builtin_bit_cast(__bf16, u);
}
static __device__ __forceinline__ ushort4 cvt4(float4 v){
    ushort4 r; r.x=f2us(v.x); r.y=f2us(v.y); r.z=f2us(v.z); r.w=f2us(v.w); return r;
}

// ---------------- routing + top-p gate (+ per-expert counts) ----------------
__global__ __launch_bounds__(256)
void k_route_gate(const float* __restrict__ s, const float* __restrict__ router_w,
                  float* __restrict__ gate_out, int* __restrict__ cnt)
{
    int tok = blockIdx.x;
    int b = tok >> 11, t = tok & (T_-1);
    const float* sbase = s + (size_t)b*NS*TD + (size_t)t*D_;
    __shared__ float rbuf[D_];
    __shared__ float part[16][17];
    __shared__ float logits[16];
    int tid = threadIdx.x;
    for (int dd = tid; dd < D_; dd += 256) {
        float acc = 0.f;
        #pragma unroll
        for (int j=0;j<NS;j++) acc += sbase[(size_t)j*TD + dd];
        rbuf[dd] = acc * 0.25f;
    }
    __syncthreads();
    int e = tid >> 4, m = tid & 15;
    const float* wr = router_w + (size_t)e*D_;
    float acc = 0.f;
    for (int k=m;k<D_;k+=16) acc += rbuf[k]*wr[k];
    part[e][m] = acc;
    __syncthreads();
    if (tid < 16) {
        float sum=0.f;
        for (int q=0;q<16;q++) sum += part[tid][q];
        logits[tid]=sum;
    }
    __syncthreads();
    if (tid==0) {
        float p[16];
        float mx=-1e30f;
        for (int i=0;i<16;i++) mx = fmaxf(mx, logits[i]);
        float sum=0.f;
        for (int i=0;i<16;i++){ p[i]=__expf(logits[i]-mx); sum+=p[i]; }
        float inv=1.0f/sum;
        for (int i=0;i<16;i++) p[i]*=inv;
        float* g = gate_out + (size_t)tok*E_;
        for (int i=0;i<16;i++){
            int rank=0; float csb=0.f;
            for (int k=0;k<16;k++){
                bool before = (p[k]>p[i]) || (p[k]==p[i] && k<i);
                if (before){ rank++; csb+=p[k]; }
            }
            bool msk = (rank==0) || (csb < 0.8f && rank < 4);
            float gv = msk ? p[i] : 0.f;
            g[i] = gv;
            if (gv > 0.f) atomicAdd(&cnt[i], 1);
        }
    }
}

// ---------------- exclusive scan of per-expert counts ----------------
__global__ void k_scan(const int* __restrict__ cnt, int* __restrict__ off)
{
    int o = 0;
    for (int e=0;e<E_;e++){ off[e]=o; o += cnt[e]; }
    off[E_] = o;
}

// ---------------- compacted slot lists ----------------
__global__ __launch_bounds__(256)
void k_fill(const float* __restrict__ gate, const int* __restrict__ off,
            int* __restrict__ cnt2, int* __restrict__ idx, int* __restrict__ eidx,
            int* __restrict__ tokmeta, int* __restrict__ nact)
{
    int tok = blockIdx.x*256 + threadIdx.x;
    if (tok >= BT) return;
    int kk = 0;
    #pragma unroll
    for (int e=0;e<E_;e++){
        float g = gate[(size_t)tok*E_+e];
        if (g > 0.0f){
            int p = atomicAdd(&cnt2[e], 1);
            int s = off[e] + p;
            idx[s] = tok;
            eidx[s] = e;
            tokmeta[tok*4 + kk] = (e<<16) | s;
            kk++;
        }
    }
    nact[tok] = kk;
}

// ---------------- inv RMS over flattened (n*d) ----------------
__global__ __launch_bounds__(256)
void k_inv_rms(const float* __restrict__ s, float* __restrict__ inv_rms)
{
    int tok=blockIdx.x; int b=tok>>11, t=tok&(T_-1);
    const float* sbase = s + (size_t)b*NS*TD + (size_t)t*D_;
    int tid=threadIdx.x;
    float ss=0.f;
    for (int k=tid;k<ND;k+=256){
        int j=k>>10, dd=k&1023;
        float v = sbase[(size_t)j*TD+dd];
        ss += v*v;
    }
    for (int off=32;off>0;off>>=1) ss += __shfl_down(ss, off, 64);
    __shared__ float red[4];
    if ((tid&63)==0) red[tid>>6]=ss;
    __syncthreads();
    if (tid==0)
        inv_rms[tok] = rsqrtf((red[0]+red[1]+red[2]+red[3])*(1.0f/ND) + EPS_);
}

// ---------------- fold mhc_norm_w * alpha into phi weights ----------------
__global__ __launch_bounds__(256)
void k_fold(const float* __restrict__ pw, const float* __restrict__ ow, const float* __restrict__ rw,
            const float* __restrict__ nw, const float* __restrict__ ap, const float* __restrict__ ao,
            const float* __restrict__ ar, float* __restrict__ Wall)
{
    int i = blockIdx.x*256 + threadIdx.x;
    if (i >= E_*24*ND) return;
    int k = i & (ND-1);
    int r = (i >> 12) % 24;
    int e = i / (24*ND);
    float w, a;
    if (r<4)      { w = pw[((size_t)e*4  + r     )*ND + k]; a = ap[e]; }
    else if (r<8) { w = ow[((size_t)e*4  + (r-4) )*ND + k]; a = ao[e]; }
    else          { w = rw[((size_t)e*16 + (r-8) )*ND + k]; a = ar[e]; }
    Wall[i] = w * a * nw[(size_t)e*ND + k];
}

// ---------------- pre-GEMM, split-K: preact += (inv_rms*stream_flat) @ Wall^T ----------------
__global__ __launch_bounds__(256)
void k_mm_pre(const float* __restrict__ s, const float* __restrict__ W,
              const float* __restrict__ scale, float* __restrict__ C)
{
    const int m0 = blockIdx.x*128;
    const int n0 = blockIdx.y*128;
    const int kz = blockIdx.z;

    __shared__ unsigned short As[128*40];
    __shared__ unsigned short Ws[128*40];

    const int tid = threadIdx.x;
    const int lane = tid & 63, w = tid >> 6;
    const int wm = (w>>1)*64, wn = (w&1)*64;
    const int lr = lane & 15, kg = lane >> 4;

    int aoff[4], boff[4];
    #pragma unroll
    for (int i=0;i<4;i++){ aoff[i] = (wm+i*16+lr)*40 + kg*8; boff[i] = (wn+i*16+lr)*40 + kg*8; }

    const int r0 = tid>>1, hh = (tid&1)*16;
    const int tok = m0 + r0;
    const int ab = tok >> 11, at = tok & 2047;
    const float* arow = s + (size_t)ab*NS*TD + (size_t)at*D_;
    const float sc = scale[tok];

    f32x4 acc[4][4] = {};

    const int kend = (kz+1)*(ND/KSPLIT);
    for (int k0=kz*(ND/KSPLIT); k0<kend; k0+=32){
        {   // stage A: f32 stream (k -> j*TD + dd), scale by inv_rms, -> bf16 LDS
            int kb = k0 + hh;
            int j = kb >> 10, dd = kb & 1023;
            const float* pa = arow + (size_t)j*TD + dd;
            #pragma unroll
            for (int q=0;q<4;q++){
                float4 av = *(const float4*)(pa + q*4);
                av.x*=sc; av.y*=sc; av.z*=sc; av.w*=sc;
                *(ushort4*)&As[r0*40 + hh + q*4] = cvt4(av);
            }
        }
        {   // stage W (Wall f32 [384][4096])
            #pragma unroll
            for (int q=0;q<4;q++){
                int k = k0 + hh + q*4;
                float4 wv = *(const float4*)&W[(size_t)(n0+r0)*ND + k];
                *(ushort4*)&Ws[r0*40 + hh + q*4] = cvt4(wv);
            }
        }
        __syncthreads();
        bf16x8 af[4], bw[4];
        #pragma unroll
        for (int i=0;i<4;i++) af[i] = *(const bf16x8*)(const void*)&As[aoff[i]];
        #pragma unroll
        for (int j=0;j<4;j++) bw[j] = *(const bf16x8*)(const void*)&Ws[boff[j]];
        #pragma unroll
        for (int i=0;i<4;i++)
            #pragma unroll
            for (int j=0;j<4;j++)
                acc[i][j] = __builtin_amdgcn_mfma_f32_16x16x32_bf16(af[i], bw[j], acc[i][j], 0,0,0);
        __syncthreads();
    }

    #pragma unroll
    for (int i=0;i<4;i++){
        #pragma unroll
        for (int r=0;r<4;r++){
            int gr = m0 + wm + i*16 + kg*4 + r;
            #pragma unroll
            for (int j=0;j<4;j++){
                int gc = n0 + wn + j*16 + lr;
                if (gc >= 384) continue;
                atomicAdd(&C[(size_t)gr*384 + gc], acc[i][j][r]);
            }
        }
    }
}

// ---------------- activations + sinkhorn ----------------
__global__ __launch_bounds__(256)
void k_act(const float* __restrict__ preact, const float* __restrict__ b_pre,
           const float* __restrict__ b_post, const float* __restrict__ b_res,
           float* __restrict__ Hpre, float* __restrict__ Hpost, float* __restrict__ Hres)
{
    int i = blockIdx.x*256 + threadIdx.x;
    int tok = i & (BT-1);
    int e = i >> 12;
    const float* pr = preact + (size_t)tok*384 + e*24;
    float* hp = Hpre  + ((size_t)e*BT+tok)*4;
    float* ho = Hpost + ((size_t)e*BT+tok)*4;
    float* hr = Hres  + ((size_t)e*BT+tok)*16;
    #pragma unroll
    for (int r=0;r<4;r++) hp[r] = sigm(pr[r] + b_pre[e*4+r]);
    #pragma unroll
    for (int r=0;r<4;r++) ho[r] = 2.0f*sigm(pr[4+r] + b_post[e*4+r]);
    float Mv[16];
    #pragma unroll
    for (int r=0;r<16;r++) Mv[r] = __expf(pr[8+r] + b_res[e*16+r]);
    #pragma unroll
    for (int it=0; it<6; it++){
        #pragma unroll
        for (int r=0;r<4;r++){
            float inv = 1.0f/(Mv[4*r]+Mv[4*r+1]+Mv[4*r+2]+Mv[4*r+3]);
            Mv[4*r]*=inv; Mv[4*r+1]*=inv; Mv[4*r+2]*=inv; Mv[4*r+3]*=inv;
        }
        #pragma unroll
        for (int c=0;c<4;c++){
            float inv = 1.0f/(Mv[c]+Mv[4+c]+Mv[8+c]+Mv[12+c]);
            Mv[c]*=inv; Mv[4+c]*=inv; Mv[8+c]*=inv; Mv[12+c]*=inv;
        }
    }
    #pragma unroll
    for (int r=0;r<16;r++) hr[r]=Mv[r];
}

// ---------------- h = sum_j Hpre_j*stream_j ; hn = rms(h)*snw -> bf16 (all experts) ----------------
__global__ __launch_bounds__(256)
void k_hn_all(const float* __restrict__ s, const float* __restrict__ Hpre,
              const float* __restrict__ snw, const int* __restrict__ off,
              const int* __restrict__ idx, const int* __restrict__ eidx,
              unsigned short* __restrict__ hn)
{
    int sl = blockIdx.x;
    if (sl >= off[E_]) return;
    int e = eidx[sl], tok = idx[sl];
    int b=tok>>11, t=tok&2047;
    const float* sbase = s + (size_t)b*NS*TD + (size_t)t*D_;
    const float* hp = Hpre + ((size_t)e*BT+tok)*4;
    float h0=hp[0], h1=hp[1], h2=hp[2], h3=hp[3];
    int tid=threadIdx.x;
    float hv[4]; float ss=0.f;
    #pragma unroll
    for (int u=0;u<4;u++){
        int dd = tid + u*256;
        float v = h0*sbase[dd] + h1*sbase[(size_t)TD+dd]
                + h2*sbase[(size_t)2*TD+dd] + h3*sbase[(size_t)3*TD+dd];
        hv[u]=v; ss += v*v;
    }
    for (int o=32;o>0;o>>=1) ss += __shfl_down(ss, o, 64);
    __shared__ float red[4];
    if ((tid&63)==0) red[tid>>6]=ss;
    __syncthreads();
    float tot = red[0]+red[1]+red[2]+red[3];
    float scale = rsqrtf(tot*(1.0f/D_) + EPS_);
    const float* sw = snw + (size_t)e*D_;
    #pragma unroll
    for (int u=0;u<4;u++){
        int dd = tid + u*256;
        hn[(size_t)sl*D_+dd] = f2us(hv[u]*scale*sw[dd]);
    }
}

// =====================================================================
// batched bf16 MFMA GEMM over experts (blockIdx.z = expert), compacted rows
// EPI: 1 = silu -> bf16 ; 2 = sigmoid -> bf16 ; 3 = * aux(bf16) -> bf16
// =====================================================================
template<int EPI>
__global__ __launch_bounds__(256)
void k_mm(const unsigned short* __restrict__ A, const float* __restrict__ Wb,
          unsigned short* __restrict__ C, const unsigned short* __restrict__ aux,
          const int* __restrict__ cnt, const int* __restrict__ off,
          int N, int K, int ldc, size_t wstride)
{
    const int e = blockIdx.z;
    const int Mact = cnt[e];
    const int m0 = blockIdx.x*128;
    if (m0 >= Mact) return;
    const int n0 = blockIdx.y*128;
    const size_t rb = off[e];
    const float* W = Wb + (size_t)e*wstride;

    __shared__ unsigned short As[128*40];
    __shared__ unsigned short Ws[128*40];

    const int tid = threadIdx.x;
    const int lane = tid & 63, w = tid >> 6;
    const int wm = (w>>1)*64, wn = (w&1)*64;
    const int lr = lane & 15, kg = lane >> 4;

    int aoff[4], boff[4];
    #pragma unroll
    for (int i=0;i<4;i++){ aoff[i] = (wm+i*16+lr)*40 + kg*8; boff[i] = (wn+i*16+lr)*40 + kg*8; }

    const int ar0 = tid>>2, ak8 = (tid&3)*8;
    const int wr0 = tid>>1, wh = (tid&1)*16;

    f32x4 acc[4][4] = {};

    for (int k0=0; k0<K; k0+=32){
        #pragma unroll
        for (int p=0;p<2;p++){
            int row = ar0 + p*64;
            uint4 v = make_uint4(0u,0u,0u,0u);
            if (m0+row < Mact && k0+ak8+8 <= K)
                v = *(const uint4*)&A[(rb+m0+row)*(size_t)K + k0 + ak8];
            *(uint4*)&As[row*40 + ak8] = v;
        }
        {
            int row = wr0;
            bool rv = (n0+row) < N;
            #pragma unroll
            for (int q=0;q<4;q++){
                int k = k0 + wh + q*4;
                float4 wv = make_float4(0.f,0.f,0.f,0.f);
                if (rv && k+4 <= K)
                    wv = *(const float4*)&W[(size_t)(n0+row)*K + k];
                *(ushort4*)&Ws[row*40 + wh + q*4] = cvt4(wv);
            }
        }
        __syncthreads();
        bf16x8 af[4], bw[4];
        #pragma unroll
        for (int i=0;i<4;i++) af[i] = *(const bf16x8*)(const void*)&As[aoff[i]];
        #pragma unroll
        for (int j=0;j<4;j++) bw[j] = *(const bf16x8*)(const void*)&Ws[boff[j]];
        #pragma unroll
        for (int i=0;i<4;i++)
            #pragma unroll
            for (int j=0;j<4;j++)
                acc[i][j] = __builtin_amdgcn_mfma_f32_16x16x32_bf16(af[i], bw[j], acc[i][j], 0,0,0);
        __syncthreads();
    }

    #pragma unroll
    for (int i=0;i<4;i++){
        #pragma unroll
        for (int r=0;r<4;r++){
            int gr = m0 + wm + i*16 + kg*4 + r;
            if (gr >= Mact) continue;
            #pragma unroll
            for (int j=0;j<4;j++){
                int gc = n0 + wn + j*16 + lr;
                if (gc >= N) continue;
                float v = acc[i][j][r];
                if (EPI==1)      v = v*sigm(v);
                else if (EPI==2) v = sigm(v);
                else             v = v*us2f(aux[(rb+gr)*(size_t)ldc + gc]);
                C[(rb+gr)*(size_t)ldc + gc] = f2us(v);
            }
        }
    }
}

// ---------------- fused gate+up GEMM: P = silu(hn@GW^T) * (hn@UW^T) ----------------
__global__ __launch_bounds__(256)
void k_mm_gateup(const unsigned short* __restrict__ A, const float* __restrict__ GWb,
                 const float* __restrict__ UWb, unsigned short* __restrict__ P,
                 const int* __restrict__ cnt, const int* __restrict__ off)
{
    const int e = blockIdx.z;
    const int Mact = cnt[e];
    const int m0 = blockIdx.x*128;
    if (m0 >= Mact) return;
    const int n0 = blockIdx.y*128;
    const size_t rb = off[e];
    const float* GW = GWb + (size_t)e*DFFN*D_;
    const float* UW = UWb + (size_t)e*DFFN*D_;

    __shared__ unsigned short As[128*40];
    __shared__ unsigned short Gs[128*40];
    __shared__ unsigned short Us[128*40];

    const int tid = threadIdx.x;
    const int lane = tid & 63, w = tid >> 6;
    const int wm = (w>>1)*64, wn = (w&1)*64;
    const int lr = lane & 15, kg = lane >> 4;

    int aoff[4], boff[4];
    #pragma unroll
    for (int i=0;i<4;i++){ aoff[i] = (wm+i*16+lr)*40 + kg*8; boff[i] = (wn+i*16+lr)*40 + kg*8; }

    const int ar0 = tid>>2, ak8 = (tid&3)*8;
    const int wr0 = tid>>1, wh = (tid&1)*16;

    f32x4 accg[4][4] = {};
    f32x4 accu[4][4] = {};

    for (int k0=0; k0<D_; k0+=32){
        #pragma unroll
        for (int p=0;p<2;p++){
            int row = ar0 + p*64;
            uint4 v = make_uint4(0u,0u,0u,0u);
            if (m0+row < Mact)
                v = *(const uint4*)&A[(rb+m0+row)*(size_t)D_ + k0 + ak8];
            *(uint4*)&As[row*40 + ak8] = v;
        }
        {
            int row = wr0;
            bool rv = (n0+row) < DFFN;
            #pragma unroll
            for (int q=0;q<4;q++){
                int k = k0 + wh + q*4;
                float4 gv = make_float4(0.f,0.f,0.f,0.f);
                float4 uv = make_float4(0.f,0.f,0.f,0.f);
                if (rv){
                    gv = *(const float4*)&GW[(size_t)(n0+row)*D_ + k];
                    uv = *(const float4*)&UW[(size_t)(n0+row)*D_ + k];
                }
                *(ushort4*)&Gs[row*40 + wh + q*4] = cvt4(gv);
                *(ushort4*)&Us[row*40 + wh + q*4] = cvt4(uv);
            }
        }
        __syncthreads();
        bf16x8 af[4], bg[4], bu[4];
        #pragma unroll
        for (int i=0;i<4;i++) af[i] = *(const bf16x8*)(const void*)&As[aoff[i]];
        #pragma unroll
        for (int j=0;j<4;j++) bg[j] = *(const bf16x8*)(const void*)&Gs[boff[j]];
        #pragma unroll
        for (int j=0;j<4;j++) bu[j] = *(const bf16x8*)(const void*)&Us[boff[j]];
        #pragma unroll
        for (int i=0;i<4;i++){
            #pragma unroll
            for (int j=0;j<4;j++){
                accg[i][j] = __builtin_amdgcn_mfma_f32_16x16x32_bf16(af[i], bg[j], accg[i][j], 0,0,0);
                accu[i][j] = __builtin_amdgcn_mfma_f32_16x16x32_bf16(af[i], bu[j], accu[i][j], 0,0,0);
            }
        }
        __syncthreads();
    }

    #pragma unroll
    for (int i=0;i<4;i++){
        #pragma unroll
        for (int r=0;r<4;r++){
            int gr = m0 + wm + i*16 + kg*4 + r;
            if (gr >= Mact) continue;
            #pragma unroll
            for (int j=0;j<4;j++){
                int gc = n0 + wn + j*16 + lr;
                if (gc >= DFFN) continue;
                float g = accg[i][j][r];
                float u = accu[i][j][r];
                P[(rb+gr)*(size_t)DFFN + gc] = f2us(g*sigm(g)*u);
            }
        }
    }
}

// ---------------- final: out[tok] = sum_e g*(Hres@stream + Hpost*outc) ----------------
__global__ __launch_bounds__(256)
void k_accum_all(const float* __restrict__ s, const float* __restrict__ gate,
                 const float* __restrict__ Hres, const float* __restrict__ Hpost,
                 const unsigned short* __restrict__ outc, const int* __restrict__ tokmeta,
                 const int* __restrict__ nact, float* __restrict__ outp)
{
    int tok = blockIdx.x;
    int b=tok>>11, t=tok&2047;
    int na = nact[tok];
    __shared__ float sR[4][16];
    __shared__ float sP[4][4];
    __shared__ float sg[4];
    __shared__ int ssl[4];
    int tid = threadIdx.x;
    if (tid < 64){
        int k = tid >> 4, r = tid & 15;
        if (k < na){
            int meta = tokmeta[tok*4 + k];
            int e = meta >> 16;
            sR[k][r] = Hres[((size_t)e*BT+tok)*16 + r];
            if (r < 4) sP[k][r] = Hpost[((size_t)e*BT+tok)*4 + r];
            if (r == 0){
                sg[k] = gate[(size_t)tok*E_ + e];
                ssl[k] = meta & 0xffff;
            }
        }
    }
    __syncthreads();
    const float* sbase = s    + (size_t)b*NS*TD + (size_t)t*D_;
    float* obase       = outp + (size_t)b*NS*TD + (size_t)t*D_;
    #pragma unroll
    for (int u=0;u<4;u++){
        int dd = tid + u*256;
        float s0=sbase[dd], s1=sbase[(size_t)TD+dd], s2=sbase[(size_t)2*TD+dd], s3=sbase[(size_t)3*TD+dd];
        float a0=0.f, a1=0.f, a2=0.f, a3=0.f;
        for (int k=0;k<na;k++){
            float g = sg[k];
            float ov = us2f(outc[(size_t)ssl[k]*D_ + dd]);
            a0 += g*(sR[k][0] *s0 + sR[k][1] *s1 + sR[k][2] *s2 + sR[k][3] *s3 + sP[k][0]*ov);
            a1 += g*(sR[k][4] *s0 + sR[k][5] *s1 + sR[k][6] *s2 + sR[k][7] *s3 + sP[k][1]*ov);
            a2 += g*(sR[k][8] *s0 + sR[k][9] *s1 + sR[k][10]*s2 + sR[k][11]*s3 + sP[k][2]*ov);
            a3 += g*(sR[k][12]*s0 + sR[k][13]*s1 + sR[k][14]*s2 + sR[k][15]*s3 + sP[k][3]*ov);
        }
        obase[dd]               = a0;
        obase[(size_t)TD+dd]    = a1;
        obase[(size_t)2*TD+dd]  = a2;
        obase[(size_t)3*TD+dd]  = a3;
    }
}

extern "C" void kernel_launch(void* const* d_in, const int* in_sizes, int n_in,
                              void* d_out, int out_size, void* d_ws, size_t ws_size,
                              hipStream_t stream)
{
    const float* s_in       = (const float*)d_in[0];
    const float* router_w   = (const float*)d_in[1];
    const float* mhc_norm_w = (const float*)d_in[2];
    const float* phi_pre_w  = (const float*)d_in[3];
    const float* phi_post_w = (const float*)d_in[4];
    const float* phi_res_w  = (const float*)d_in[5];
    const float* b_pre      = (const float*)d_in[6];
    const float* b_post     = (const float*)d_in[7];
    const float* b_res      = (const float*)d_in[8];
    const float* alpha_pre  = (const float*)d_in[9];
    const float* alpha_post = (const float*)d_in[10];
    const float* alpha_res  = (const float*)d_in[11];
    const float* sw_norm_w  = (const float*)d_in[12];
    const float* wd_w       = (const float*)d_in[13];
    const float* wu_w       = (const float*)d_in[14];
    const float* gate_w     = (const float*)d_in[15];
    const float* up_w       = (const float*)d_in[16];
    const float* down_w     = (const float*)d_in[17];

    float* out_stream = (float*)d_out;
    float* gate_out   = out_stream + (size_t)B_*NS*T_*D_;

    char* w = (char*)d_ws;
    int* cnt   = (int*)w;        // [16]
    int* cnt2  = cnt + 16;       // [16]
    int* off   = cnt + 32;       // [17]
    w += 256;
    int* idx     = (int*)w; w += (size_t)RCAP*4;
    int* eidx    = (int*)w; w += (size_t)RCAP*4;
    int* tokmeta = (int*)w; w += (size_t)BT*4*4;
    int* nact    = (int*)w; w += (size_t)BT*4;
    float* inv_rms = (float*)w; w += (size_t)BT*4;
    float* Wall    = (float*)w; w += (size_t)E_*24*ND*4;
    float* preact  = (float*)w; w += (size_t)BT*384*4;
    float* Hpre    = (float*)w; w += (size_t)E_*BT*4*4;
    float* Hpost   = (float*)w; w += (size_t)E_*BT*4*4;
    float* Hres    = (float*)w; w += (size_t)E_*BT*16*4;
    unsigned short* hn   = (unsigned short*)w; w += (size_t)RCAP*D_*2;
    unsigned short* Abuf = (unsigned short*)w; w += (size_t)RCAP*D_*2;
    unsigned short* Pbuf = (unsigned short*)w; w += (size_t)RCAP*DFFN*2;
    unsigned short* gsig = hn;    // hn dead after gate/up + wd stages
    unsigned short* outc = Abuf;  // Abuf dead after wu stage

    hipMemsetAsync(cnt, 0, 256, stream);
    hipMemsetAsync(preact, 0, (size_t)BT*384*4, stream);

    k_route_gate<<<BT,256,0,stream>>>(s_in, router_w, gate_out, cnt);
    k_scan<<<1,1,0,stream>>>(cnt, off);
    k_fill<<<BT/256,256,0,stream>>>(gate_out, off, cnt2, idx, eidx, tokmeta, nact);
    k_inv_rms<<<BT,256,0,stream>>>(s_in, inv_rms);
    {
        int tot = E_*24*ND;
        k_fold<<<(tot+255)/256,256,0,stream>>>(phi_pre_w, phi_post_w, phi_res_w,
                                               mhc_norm_w, alpha_pre, alpha_post, alpha_res, Wall);
    }
    k_mm_pre<<<dim3(BT/128, 3, KSPLIT),256,0,stream>>>(s_in, Wall, inv_rms, preact);
    k_act<<<(BT*E_)/256,256,0,stream>>>(preact, b_pre, b_post, b_res, Hpre, Hpost, Hres);

    const int MT   = BT/128;           // 32 m-tiles max per expert (early-exit past cnt)
    const int NT_D = D_/128;           // 8
    const int NT_F = (DFFN+127)/128;   // 13

    k_hn_all<<<RCAP,256,0,stream>>>(s_in, Hpre, sw_norm_w, off, idx, eidx, hn);
    // gate+up fused (reads hn, writes Pbuf)
    k_mm_gateup<<<dim3(MT,NT_F,E_),256,0,stream>>>(hn, gate_w, up_w, Pbuf, cnt, off);
    // wd: Abuf = silu(hn @ wd^T)           (hn dead afterwards)
    k_mm<1><<<dim3(MT,NT_D,E_),256,0,stream>>>(
        hn, wd_w, Abuf, nullptr, cnt, off, D_, D_, D_, (size_t)D_*D_);
    // wu: gsig(=hn) = sigmoid(Abuf @ wu^T) (Abuf dead afterwards)
    k_mm<2><<<dim3(MT,NT_D,E_),256,0,stream>>>(
        Abuf, wu_w, gsig, nullptr, cnt, off, D_, D_, D_, (size_t)D_*D_);
    // down: outc(=Abuf) = gsig * (Pbuf @ down^T)
    k_mm<3><<<dim3(MT,NT_D,E_),256,0,stream>>>(
        Pbuf, down_w, outc, gsig, cnt, off, D_, DFFN, D_, (size_t)D_*DFFN);
    k_accum_all<<<BT,256,0,stream>>>(s_in, gate_out, Hres, Hpost, outc, tokmeta, nact, out_stream);
}

// Round 2
// 2679.419 us; speedup vs baseline: 2.5526x; 1.5969x over previous
//
#include <hip/hip_runtime.h>

#define B_    2
#define NS    4
#define T_    2048
#define D_    1024
#define E_    16
#define ND    4096
#define DFFN  1656
#define DFFNP 1664
#define BT    4096
#define TD    (T_*D_)
#define RCAP  16384
#define KSPLIT 4
#define EPS_  1.1920929e-7f

typedef __bf16 bf16x8 __attribute__((ext_vector_type(8)));
typedef float  f32x4  __attribute__((ext_vector_type(4)));

static __device__ __forceinline__ float sigm(float x){ return 1.0f/(1.0f+__expf(-x)); }
static __device__ __forceinline__ unsigned short f2us(float x){
    return __builtin_bit_cast(unsigned short, (__bf16)x);
}
static __device__ __forceinline__ float us2f(unsigned short u){
    return (float)__builtin_bit_cast(__bf16, u);
}
static __device__ __forceinline__ ushort4 cvt4(float4 v){
    ushort4 r; r.x=f2us(v.x); r.y=f2us(v.y); r.z=f2us(v.z); r.w=f2us(v.w); return r;
}
// async global -> LDS, 16B per lane; LDS base must be wave-uniform
static __device__ __forceinline__ void gl16(const void* g, void* l){
    __builtin_amdgcn_global_load_lds(
        (__attribute__((address_space(1))) void*)(g),
        (__attribute__((address_space(3))) void*)(l), 16, 0, 0);
}

// ---------------- routing + top-p gate (+ per-expert counts) ----------------
__global__ __launch_bounds__(256)
void k_route_gate(const float* __restrict__ s, const float* __restrict__ router_w,
                  float* __restrict__ gate_out, int* __restrict__ cnt)
{
    int tok = blockIdx.x;
    int b = tok >> 11, t = tok & (T_-1);
    const float* sbase = s + (size_t)b*NS*TD + (size_t)t*D_;
    __shared__ float rbuf[D_];
    __shared__ float part[16][17];
    __shared__ float logits[16];
    int tid = threadIdx.x;
    for (int dd = tid; dd < D_; dd += 256) {
        float acc = 0.f;
        #pragma unroll
        for (int j=0;j<NS;j++) acc += sbase[(size_t)j*TD + dd];
        rbuf[dd] = acc * 0.25f;
    }
    __syncthreads();
    int e = tid >> 4, m = tid & 15;
    const float* wr = router_w + (size_t)e*D_;
    float acc = 0.f;
    for (int k=m;k<D_;k+=16) acc += rbuf[k]*wr[k];
    part[e][m] = acc;
    __syncthreads();
    if (tid < 16) {
        float sum=0.f;
        for (int q=0;q<16;q++) sum += part[tid][q];
        logits[tid]=sum;
    }
    __syncthreads();
    if (tid==0) {
        float p[16];
        float mx=-1e30f;
        for (int i=0;i<16;i++) mx = fmaxf(mx, logits[i]);
        float sum=0.f;
        for (int i=0;i<16;i++){ p[i]=__expf(logits[i]-mx); sum+=p[i]; }
        float inv=1.0f/sum;
        for (int i=0;i<16;i++) p[i]*=inv;
        float* g = gate_out + (size_t)tok*E_;
        for (int i=0;i<16;i++){
            int rank=0; float csb=0.f;
            for (int k=0;k<16;k++){
                bool before = (p[k]>p[i]) || (p[k]==p[i] && k<i);
                if (before){ rank++; csb+=p[k]; }
            }
            bool msk = (rank==0) || (csb < 0.8f && rank < 4);
            float gv = msk ? p[i] : 0.f;
            g[i] = gv;
            if (gv > 0.f) atomicAdd(&cnt[i], 1);
        }
    }
}

// ---------------- exclusive scan of per-expert counts ----------------
__global__ void k_scan(const int* __restrict__ cnt, int* __restrict__ off)
{
    int o = 0;
    for (int e=0;e<E_;e++){ off[e]=o; o += cnt[e]; }
    off[E_] = o;
}

// ---------------- compacted slot lists ----------------
__global__ __launch_bounds__(256)
void k_fill(const float* __restrict__ gate, const int* __restrict__ off,
            int* __restrict__ cnt2, int* __restrict__ idx, int* __restrict__ eidx,
            int* __restrict__ tokmeta, int* __restrict__ nact)
{
    int tok = blockIdx.x*256 + threadIdx.x;
    if (tok >= BT) return;
    int kk = 0;
    #pragma unroll
    for (int e=0;e<E_;e++){
        float g = gate[(size_t)tok*E_+e];
        if (g > 0.0f){
            int p = atomicAdd(&cnt2[e], 1);
            int s = off[e] + p;
            idx[s] = tok;
            eidx[s] = e;
            tokmeta[tok*4 + kk] = (e<<16) | s;
            kk++;
        }
    }
    nact[tok] = kk;
}

// ---------------- rms over (n*d) fused with scaled bf16 transposed copy ----------------
__global__ __launch_bounds__(256)
void k_rmsxb(const float* __restrict__ s, unsigned short* __restrict__ xb)
{
    int tok=blockIdx.x; int b=tok>>11, t=tok&(T_-1);
    const float* sbase = s + (size_t)b*NS*TD + (size_t)t*D_;
    int tid=threadIdx.x;
    float4 v[4]; float ss=0.f;
    #pragma unroll
    for (int j=0;j<4;j++){
        v[j] = *(const float4*)(sbase + (size_t)j*TD + tid*4);
        ss += v[j].x*v[j].x + v[j].y*v[j].y + v[j].z*v[j].z + v[j].w*v[j].w;
    }
    for (int o=32;o>0;o>>=1) ss += __shfl_down(ss,o,64);
    __shared__ float red[4];
    if ((tid&63)==0) red[tid>>6]=ss;
    __syncthreads();
    float sc = rsqrtf((red[0]+red[1]+red[2]+red[3])*(1.0f/ND)+EPS_);
    #pragma unroll
    for (int j=0;j<4;j++){
        float4 a=v[j]; a.x*=sc;a.y*=sc;a.z*=sc;a.w*=sc;
        *(ushort4*)(xb + (size_t)tok*ND + j*1024 + tid*4) = cvt4(a);
    }
}

// ---------------- fold mhc_norm_w * alpha into phi weights -> bf16 ----------------
__global__ __launch_bounds__(256)
void k_fold(const float* __restrict__ pw, const float* __restrict__ ow, const float* __restrict__ rw,
            const float* __restrict__ nw, const float* __restrict__ ap, const float* __restrict__ ao,
            const float* __restrict__ ar, unsigned short* __restrict__ Wallb)
{
    int i = blockIdx.x*256 + threadIdx.x;
    if (i >= E_*24*ND) return;
    int k = i & (ND-1);
    int r = (i >> 12) % 24;
    int e = i / (24*ND);
    float w, a;
    if (r<4)      { w = pw[((size_t)e*4  + r     )*ND + k]; a = ap[e]; }
    else if (r<8) { w = ow[((size_t)e*4  + (r-4) )*ND + k]; a = ao[e]; }
    else          { w = rw[((size_t)e*16 + (r-8) )*ND + k]; a = ar[e]; }
    Wallb[i] = f2us(w * a * nw[(size_t)e*ND + k]);
}

// ---------------- f32 -> bf16 bulk convert ----------------
__global__ __launch_bounds__(256)
void k_cvt(const float* __restrict__ src, unsigned short* __restrict__ dst, size_t n)
{
    size_t i = ((size_t)blockIdx.x*256 + threadIdx.x)*8;
    if (i >= n) return;
    float4 a = *(const float4*)(src+i);
    float4 b = *(const float4*)(src+i+4);
    *(ushort4*)(dst+i)   = cvt4(a);
    *(ushort4*)(dst+i+4) = cvt4(b);
}

// ---------------- down_w f32 [*, 1656] -> bf16 [*, 1664] zero-padded ----------------
__global__ __launch_bounds__(256)
void k_cvt_dw(const float* __restrict__ src, unsigned short* __restrict__ dst)
{
    int r = blockIdx.x; int tid = threadIdx.x;    // 16384 rows
    const float* s = src + (size_t)r*DFFN;
    unsigned short* d = dst + (size_t)r*DFFNP;
    int c = tid*8;
    if (c >= DFFNP) return;
    if (c < DFFN){
        float4 a = *(const float4*)(s+c);
        float4 b = *(const float4*)(s+c+4);
        *(ushort4*)(d+c)   = cvt4(a);
        *(ushort4*)(d+c+4) = cvt4(b);
    } else {
        *(ushort4*)(d+c)   = make_ushort4(0,0,0,0);
        *(ushort4*)(d+c+4) = make_ushort4(0,0,0,0);
    }
}

// ---------------- pre-GEMM split-K, bf16 both sides, gload_lds staging ----------------
__global__ __launch_bounds__(256)
void k_mm_pre(const unsigned short* __restrict__ A, const unsigned short* __restrict__ Wb,
              float* __restrict__ C)
{
    const int m0 = blockIdx.x*128;
    const int n0 = blockIdx.y*128;
    const int kz = blockIdx.z;

    __shared__ unsigned short As[128*32];
    __shared__ unsigned short Ws[128*32];

    const int tid = threadIdx.x;
    const int lane = tid & 63, w = tid >> 6;
    const int wm = (w>>1)*64, wn = (w&1)*64;
    const int lr = lane & 15, kg = lane >> 4;
    const int srow = lane >> 2, sk = (lane & 3)*8;

    int aoff[4], boff[4];
    #pragma unroll
    for (int i=0;i<4;i++){ aoff[i] = (wm+i*16+lr)*32 + kg*8; boff[i] = (wn+i*16+lr)*32 + kg*8; }

    f32x4 acc[4][4] = {};

    const int kbeg = kz*(ND/KSPLIT), kend2 = kbeg + ND/KSPLIT;
    for (int k0=kbeg; k0<kend2; k0+=32){
        #pragma unroll
        for (int c=0;c<2;c++){
            int q = w + c*4;
            int row = q*16 + srow;
            gl16(&A [(size_t)(m0+row)*ND + k0 + sk], &As[q*512]);
            gl16(&Wb[(size_t)(n0+row)*ND + k0 + sk], &Ws[q*512]);
        }
        __syncthreads();
        bf16x8 af[4], bw[4];
        #pragma unroll
        for (int i=0;i<4;i++) af[i] = *(const bf16x8*)(const void*)&As[aoff[i]];
        #pragma unroll
        for (int j=0;j<4;j++) bw[j] = *(const bf16x8*)(const void*)&Ws[boff[j]];
        #pragma unroll
        for (int i=0;i<4;i++)
            #pragma unroll
            for (int j=0;j<4;j++)
                acc[i][j] = __builtin_amdgcn_mfma_f32_16x16x32_bf16(af[i], bw[j], acc[i][j], 0,0,0);
        __syncthreads();
    }

    #pragma unroll
    for (int i=0;i<4;i++){
        #pragma unroll
        for (int r=0;r<4;r++){
            int gr = m0 + wm + i*16 + kg*4 + r;
            #pragma unroll
            for (int j=0;j<4;j++){
                int gc = n0 + wn + j*16 + lr;
                atomicAdd(&C[(size_t)gr*384 + gc], acc[i][j][r]);
            }
        }
    }
}

// ---------------- activations + sinkhorn ----------------
__global__ __launch_bounds__(256)
void k_act(const float* __restrict__ preact, const float* __restrict__ b_pre,
           const float* __restrict__ b_post, const float* __restrict__ b_res,
           float* __restrict__ Hpre, float* __restrict__ Hpost, float* __restrict__ Hres)
{
    int i = blockIdx.x*256 + threadIdx.x;
    int tok = i & (BT-1);
    int e = i >> 12;
    const float* pr = preact + (size_t)tok*384 + e*24;
    float* hp = Hpre  + ((size_t)e*BT+tok)*4;
    float* ho = Hpost + ((size_t)e*BT+tok)*4;
    float* hr = Hres  + ((size_t)e*BT+tok)*16;
    #pragma unroll
    for (int r=0;r<4;r++) hp[r] = sigm(pr[r] + b_pre[e*4+r]);
    #pragma unroll
    for (int r=0;r<4;r++) ho[r] = 2.0f*sigm(pr[4+r] + b_post[e*4+r]);
    float Mv[16];
    #pragma unroll
    for (int r=0;r<16;r++) Mv[r] = __expf(pr[8+r] + b_res[e*16+r]);
    #pragma unroll
    for (int it=0; it<6; it++){
        #pragma unroll
        for (int r=0;r<4;r++){
            float inv = 1.0f/(Mv[4*r]+Mv[4*r+1]+Mv[4*r+2]+Mv[4*r+3]);
            Mv[4*r]*=inv; Mv[4*r+1]*=inv; Mv[4*r+2]*=inv; Mv[4*r+3]*=inv;
        }
        #pragma unroll
        for (int c=0;c<4;c++){
            float inv = 1.0f/(Mv[c]+Mv[4+c]+Mv[8+c]+Mv[12+c]);
            Mv[c]*=inv; Mv[4+c]*=inv; Mv[8+c]*=inv; Mv[12+c]*=inv;
        }
    }
    #pragma unroll
    for (int r=0;r<16;r++) hr[r]=Mv[r];
}

// ---------------- h = sum_j Hpre_j*stream_j ; hn = rms(h)*snw -> bf16 ----------------
__global__ __launch_bounds__(256)
void k_hn_all(const float* __restrict__ s, const float* __restrict__ Hpre,
              const float* __restrict__ snw, const int* __restrict__ off,
              const int* __restrict__ idx, const int* __restrict__ eidx,
              unsigned short* __restrict__ hn)
{
    int sl = blockIdx.x;
    if (sl >= off[E_]) return;
    int e = eidx[sl], tok = idx[sl];
    int b=tok>>11, t=tok&2047;
    const float* sbase = s + (size_t)b*NS*TD + (size_t)t*D_;
    const float* hp = Hpre + ((size_t)e*BT+tok)*4;
    float h0=hp[0], h1=hp[1], h2=hp[2], h3=hp[3];
    int tid=threadIdx.x;
    float hv[4]; float ss=0.f;
    #pragma unroll
    for (int u=0;u<4;u++){
        int dd = tid + u*256;
        float v = h0*sbase[dd] + h1*sbase[(size_t)TD+dd]
                + h2*sbase[(size_t)2*TD+dd] + h3*sbase[(size_t)3*TD+dd];
        hv[u]=v; ss += v*v;
    }
    for (int o=32;o>0;o>>=1) ss += __shfl_down(ss, o, 64);
    __shared__ float red[4];
    if ((tid&63)==0) red[tid>>6]=ss;
    __syncthreads();
    float tot = red[0]+red[1]+red[2]+red[3];
    float scale = rsqrtf(tot*(1.0f/D_) + EPS_);
    const float* sw = snw + (size_t)e*D_;
    #pragma unroll
    for (int u=0;u<4;u++){
        int dd = tid + u*256;
        hn[(size_t)sl*D_+dd] = f2us(hv[u]*scale*sw[dd]);
    }
}

// =====================================================================
// batched bf16 MFMA GEMM over experts; gload_lds staging; bf16 weights
// EPI: 1 = silu ; 2 = sigmoid ; 3 = * aux(bf16)
// =====================================================================
template<int EPI>
__global__ __launch_bounds__(256)
void k_mm(const unsigned short* __restrict__ A, const unsigned short* __restrict__ Wb,
          unsigned short* __restrict__ C, const unsigned short* __restrict__ aux,
          const int* __restrict__ cnt, const int* __restrict__ off,
          int N, int K, int ldc, size_t wstride)
{
    const int e = blockIdx.z;
    const int Mact = cnt[e];
    const int m0 = blockIdx.x*128;
    if (m0 >= Mact) return;
    const int n0 = blockIdx.y*128;
    const size_t rb = off[e];
    const unsigned short* W = Wb + (size_t)e*wstride;

    __shared__ unsigned short As[128*32];
    __shared__ unsigned short Ws[128*32];

    const int tid = threadIdx.x;
    const int lane = tid & 63, w = tid >> 6;
    const int wm = (w>>1)*64, wn = (w&1)*64;
    const int lr = lane & 15, kg = lane >> 4;
    const int srow = lane >> 2, sk = (lane & 3)*8;

    int aoff[4], boff[4];
    #pragma unroll
    for (int i=0;i<4;i++){ aoff[i] = (wm+i*16+lr)*32 + kg*8; boff[i] = (wn+i*16+lr)*32 + kg*8; }

    f32x4 acc[4][4] = {};

    for (int k0=0; k0<K; k0+=32){
        #pragma unroll
        for (int c=0;c<2;c++){
            int q = w + c*4;
            int row = q*16 + srow;
            int rA = m0+row; if (rA >= Mact) rA = Mact-1;
            int rW = n0+row; if (rW >= N)    rW = N-1;
            gl16(&A[(rb+rA)*(size_t)K + k0 + sk], &As[q*512]);
            gl16(&W[(size_t)rW*K + k0 + sk],      &Ws[q*512]);
        }
        __syncthreads();
        bf16x8 af[4], bw[4];
        #pragma unroll
        for (int i=0;i<4;i++) af[i] = *(const bf16x8*)(const void*)&As[aoff[i]];
        #pragma unroll
        for (int j=0;j<4;j++) bw[j] = *(const bf16x8*)(const void*)&Ws[boff[j]];
        #pragma unroll
        for (int i=0;i<4;i++)
            #pragma unroll
            for (int j=0;j<4;j++)
                acc[i][j] = __builtin_amdgcn_mfma_f32_16x16x32_bf16(af[i], bw[j], acc[i][j], 0,0,0);
        __syncthreads();
    }

    #pragma unroll
    for (int i=0;i<4;i++){
        #pragma unroll
        for (int r=0;r<4;r++){
            int gr = m0 + wm + i*16 + kg*4 + r;
            if (gr >= Mact) continue;
            #pragma unroll
            for (int j=0;j<4;j++){
                int gc = n0 + wn + j*16 + lr;
                if (gc >= N) continue;
                float v = acc[i][j][r];
                if (EPI==1)      v = v*sigm(v);
                else if (EPI==2) v = sigm(v);
                else             v = v*us2f(aux[(rb+gr)*(size_t)ldc + gc]);
                C[(rb+gr)*(size_t)ldc + gc] = f2us(v);
            }
        }
    }
}

// ---------------- fused gate+up GEMM: P = silu(hn@GW^T) * (hn@UW^T), bf16 W ----------------
__global__ __launch_bounds__(256)
void k_mm_gateup(const unsigned short* __restrict__ A, const unsigned short* __restrict__ GWb,
                 const unsigned short* __restrict__ UWb, unsigned short* __restrict__ P,
                 const int* __restrict__ cnt, const int* __restrict__ off)
{
    const int e = blockIdx.z;
    const int Mact = cnt[e];
    const int m0 = blockIdx.x*128;
    if (m0 >= Mact) return;
    const int n0 = blockIdx.y*128;
    const size_t rb = off[e];
    const unsigned short* GW = GWb + (size_t)e*DFFN*D_;
    const unsigned short* UW = UWb + (size_t)e*DFFN*D_;

    __shared__ unsigned short As[128*32];
    __shared__ unsigned short Gs[128*32];
    __shared__ unsigned short Us[128*32];

    const int tid = threadIdx.x;
    const int lane = tid & 63, w = tid >> 6;
    const int wm = (w>>1)*64, wn = (w&1)*64;
    const int lr = lane & 15, kg = lane >> 4;
    const int srow = lane >> 2, sk = (lane & 3)*8;

    int aoff[4], boff[4];
    #pragma unroll
    for (int i=0;i<4;i++){ aoff[i] = (wm+i*16+lr)*32 + kg*8; boff[i] = (wn+i*16+lr)*32 + kg*8; }

    f32x4 accg[4][4] = {};
    f32x4 accu[4][4] = {};

    for (int k0=0; k0<D_; k0+=32){
        #pragma unroll
        for (int c=0;c<2;c++){
            int q = w + c*4;
            int row = q*16 + srow;
            int rA = m0+row; if (rA >= Mact) rA = Mact-1;
            int rW = n0+row; if (rW >= DFFN) rW = DFFN-1;
            gl16(&A[(rb+rA)*(size_t)D_ + k0 + sk], &As[q*512]);
            gl16(&GW[(size_t)rW*D_ + k0 + sk],     &Gs[q*512]);
            gl16(&UW[(size_t)rW*D_ + k0 + sk],     &Us[q*512]);
        }
        __syncthreads();
        bf16x8 af[4], bg[4], bu[4];
        #pragma unroll
        for (int i=0;i<4;i++) af[i] = *(const bf16x8*)(const void*)&As[aoff[i]];
        #pragma unroll
        for (int j=0;j<4;j++) bg[j] = *(const bf16x8*)(const void*)&Gs[boff[j]];
        #pragma unroll
        for (int j=0;j<4;j++) bu[j] = *(const bf16x8*)(const void*)&Us[boff[j]];
        #pragma unroll
        for (int i=0;i<4;i++){
            #pragma unroll
            for (int j=0;j<4;j++){
                accg[i][j] = __builtin_amdgcn_mfma_f32_16x16x32_bf16(af[i], bg[j], accg[i][j], 0,0,0);
                accu[i][j] = __builtin_amdgcn_mfma_f32_16x16x32_bf16(af[i], bu[j], accu[i][j], 0,0,0);
            }
        }
        __syncthreads();
    }

    #pragma unroll
    for (int i=0;i<4;i++){
        #pragma unroll
        for (int r=0;r<4;r++){
            int gr = m0 + wm + i*16 + kg*4 + r;
            if (gr >= Mact) continue;
            #pragma unroll
            for (int j=0;j<4;j++){
                int gc = n0 + wn + j*16 + lr;   // < 1664 always (13*128 grid)
                float g = accg[i][j][r];
                float u = accu[i][j][r];
                P[(rb+gr)*(size_t)DFFNP + gc] = (gc < DFFN) ? f2us(g*sigm(g)*u)
                                                            : (unsigned short)0;
            }
        }
    }
}

// ---------------- final: out[tok] = sum_e g*(Hres@stream + Hpost*outc) ----------------
__global__ __launch_bounds__(256)
void k_accum_all(const float* __restrict__ s, const float* __restrict__ gate,
                 const float* __restrict__ Hres, const float* __restrict__ Hpost,
                 const unsigned short* __restrict__ outc, const int* __restrict__ tokmeta,
                 const int* __restrict__ nact, float* __restrict__ outp)
{
    int tok = blockIdx.x;
    int b=tok>>11, t=tok&2047;
    int na = nact[tok];
    __shared__ float sR[4][16];
    __shared__ float sP[4][4];
    __shared__ float sg[4];
    __shared__ int ssl[4];
    int tid = threadIdx.x;
    if (tid < 64){
        int k = tid >> 4, r = tid & 15;
        if (k < na){
            int meta = tokmeta[tok*4 + k];
            int e = meta >> 16;
            sR[k][r] = Hres[((size_t)e*BT+tok)*16 + r];
            if (r < 4) sP[k][r] = Hpost[((size_t)e*BT+tok)*4 + r];
            if (r == 0){
                sg[k] = gate[(size_t)tok*E_ + e];
                ssl[k] = meta & 0xffff;
            }
        }
    }
    __syncthreads();
    const float* sbase = s    + (size_t)b*NS*TD + (size_t)t*D_;
    float* obase       = outp + (size_t)b*NS*TD + (size_t)t*D_;
    #pragma unroll
    for (int u=0;u<4;u++){
        int dd = tid + u*256;
        float s0=sbase[dd], s1=sbase[(size_t)TD+dd], s2=sbase[(size_t)2*TD+dd], s3=sbase[(size_t)3*TD+dd];
        float a0=0.f, a1=0.f, a2=0.f, a3=0.f;
        for (int k=0;k<na;k++){
            float g = sg[k];
            float ov = us2f(outc[(size_t)ssl[k]*D_ + dd]);
            a0 += g*(sR[k][0] *s0 + sR[k][1] *s1 + sR[k][2] *s2 + sR[k][3] *s3 + sP[k][0]*ov);
            a1 += g*(sR[k][4] *s0 + sR[k][5] *s1 + sR[k][6] *s2 + sR[k][7] *s3 + sP[k][1]*ov);
            a2 += g*(sR[k][8] *s0 + sR[k][9] *s1 + sR[k][10]*s2 + sR[k][11]*s3 + sP[k][2]*ov);
            a3 += g*(sR[k][12]*s0 + sR[k][13]*s1 + sR[k][14]*s2 + sR[k][15]*s3 + sP[k][3]*ov);
        }
        obase[dd]               = a0;
        obase[(size_t)TD+dd]    = a1;
        obase[(size_t)2*TD+dd]  = a2;
        obase[(size_t)3*TD+dd]  = a3;
    }
}

extern "C" void kernel_launch(void* const* d_in, const int* in_sizes, int n_in,
                              void* d_out, int out_size, void* d_ws, size_t ws_size,
                              hipStream_t stream)
{
    const float* s_in       = (const float*)d_in[0];
    const float* router_w   = (const float*)d_in[1];
    const float* mhc_norm_w = (const float*)d_in[2];
    const float* phi_pre_w  = (const float*)d_in[3];
    const float* phi_post_w = (const float*)d_in[4];
    const float* phi_res_w  = (const float*)d_in[5];
    const float* b_pre      = (const float*)d_in[6];
    const float* b_post     = (const float*)d_in[7];
    const float* b_res      = (const float*)d_in[8];
    const float* alpha_pre  = (const float*)d_in[9];
    const float* alpha_post = (const float*)d_in[10];
    const float* alpha_res  = (const float*)d_in[11];
    const float* sw_norm_w  = (const float*)d_in[12];
    const float* wd_w       = (const float*)d_in[13];
    const float* wu_w       = (const float*)d_in[14];
    const float* gate_w     = (const float*)d_in[15];
    const float* up_w       = (const float*)d_in[16];
    const float* down_w     = (const float*)d_in[17];

    float* out_stream = (float*)d_out;
    float* gate_out   = out_stream + (size_t)B_*NS*T_*D_;

    char* w = (char*)d_ws;
    int* cnt   = (int*)w;        // [16]
    int* cnt2  = cnt + 16;       // [16]
    int* off   = cnt + 32;       // [17]
    w += 256;
    int* idx     = (int*)w; w += (size_t)RCAP*4;
    int* eidx    = (int*)w; w += (size_t)RCAP*4;
    int* tokmeta = (int*)w; w += (size_t)BT*4*4;
    int* nact    = (int*)w; w += (size_t)BT*4;
    unsigned short* Wallb = (unsigned short*)w; w += (size_t)E_*24*ND*2;
    float* preact  = (float*)w; w += (size_t)BT*384*4;
    float* Hpre    = (float*)w; w += (size_t)E_*BT*4*4;
    float* Hpost   = (float*)w; w += (size_t)E_*BT*4*4;
    float* Hres    = (float*)w; w += (size_t)E_*BT*16*4;
    unsigned short* hn   = (unsigned short*)w; w += (size_t)(RCAP+128)*D_*2;
    unsigned short* Abuf = (unsigned short*)w; w += (size_t)(RCAP+128)*D_*2;
    unsigned short* Pbuf = (unsigned short*)w; w += (size_t)(RCAP+128)*DFFNP*2;
    unsigned short* scr  = (unsigned short*)w; w += (size_t)(E_*DFFN*D_*2 + E_*D_*DFFNP)*2;

    unsigned short* xb   = Abuf;                 // dead after k_mm_pre; Abuf used later
    unsigned short* gsig = hn;                   // hn dead after gateup + wd
    unsigned short* outc = Abuf;                 // Abuf dead after wu
    unsigned short* gwb  = scr;                                   // phase 1
    unsigned short* uwb  = scr + (size_t)E_*DFFN*D_;
    unsigned short* wdb  = scr;                                   // phase 2
    unsigned short* wub  = scr + (size_t)E_*D_*D_;
    unsigned short* dwb  = scr + (size_t)2*E_*D_*D_;

    hipMemsetAsync(cnt, 0, 256, stream);
    hipMemsetAsync(preact, 0, (size_t)BT*384*4, stream);

    k_route_gate<<<BT,256,0,stream>>>(s_in, router_w, gate_out, cnt);
    k_scan<<<1,1,0,stream>>>(cnt, off);
    k_fill<<<BT/256,256,0,stream>>>(gate_out, off, cnt2, idx, eidx, tokmeta, nact);
    k_rmsxb<<<BT,256,0,stream>>>(s_in, xb);
    {
        int tot = E_*24*ND;
        k_fold<<<(tot+255)/256,256,0,stream>>>(phi_pre_w, phi_post_w, phi_res_w,
                                               mhc_norm_w, alpha_pre, alpha_post, alpha_res, Wallb);
    }
    {   // phase-1 weight converts (gate, up)
        size_t n = (size_t)E_*DFFN*D_;
        k_cvt<<<(unsigned)(n/2048),256,0,stream>>>(gate_w, gwb, n);
        k_cvt<<<(unsigned)(n/2048),256,0,stream>>>(up_w,   uwb, n);
    }
    k_mm_pre<<<dim3(BT/128, 3, KSPLIT),256,0,stream>>>(xb, Wallb, preact);
    k_act<<<(BT*E_)/256,256,0,stream>>>(preact, b_pre, b_post, b_res, Hpre, Hpost, Hres);
    k_hn_all<<<RCAP,256,0,stream>>>(s_in, Hpre, sw_norm_w, off, idx, eidx, hn);

    const int MT   = BT/128;            // 32 m-tiles (early-exit past cnt)
    const int NT_D = D_/128;            // 8
    const int NT_F = DFFNP/128;         // 13

    // gate+up fused -> Pbuf
    k_mm_gateup<<<dim3(MT,NT_F,E_),256,0,stream>>>(hn, gwb, uwb, Pbuf, cnt, off);

    {   // phase-2 weight converts (wd, wu, down) -- reuse scratch after gateup
        size_t n = (size_t)E_*D_*D_;
        k_cvt<<<(unsigned)(n/2048),256,0,stream>>>(wd_w, wdb, n);
        k_cvt<<<(unsigned)(n/2048),256,0,stream>>>(wu_w, wub, n);
        k_cvt_dw<<<E_*D_,256,0,stream>>>(down_w, dwb);
    }
    // wd: Abuf = silu(hn @ wd^T)
    k_mm<1><<<dim3(MT,NT_D,E_),256,0,stream>>>(
        hn, wdb, Abuf, nullptr, cnt, off, D_, D_, D_, (size_t)D_*D_);
    // wu: gsig(=hn) = sigmoid(Abuf @ wu^T)
    k_mm<2><<<dim3(MT,NT_D,E_),256,0,stream>>>(
        Abuf, wub, gsig, nullptr, cnt, off, D_, D_, D_, (size_t)D_*D_);
    // down: outc(=Abuf) = gsig * (Pbuf @ down^T)
    k_mm<3><<<dim3(MT,NT_D,E_),256,0,stream>>>(
        Pbuf, dwb, outc, gsig, cnt, off, D_, DFFNP, D_, (size_t)D_*DFFNP);
    k_accum_all<<<BT,256,0,stream>>>(s_in, gate_out, Hres, Hpost, outc, tokmeta, nact, out_stream);
}

// Round 3
// 1548.083 us; speedup vs baseline: 4.4180x; 1.7308x over previous
//
#include <hip/hip_runtime.h>

#define B_    2
#define NS    4
#define T_    2048
#define D_    1024
#define E_    16
#define ND    4096
#define DFFN  1656
#define DFFNP 1664
#define BT    4096
#define TD    (T_*D_)
#define RCAP  16384
#define KSPLIT 8
#define EPS_  1.1920929e-7f

typedef __bf16 bf16x8 __attribute__((ext_vector_type(8)));
typedef float  f32x4  __attribute__((ext_vector_type(4)));

static __device__ __forceinline__ float sigm(float x){ return 1.0f/(1.0f+__expf(-x)); }
static __device__ __forceinline__ unsigned short f2us(float x){
    return __builtin_bit_cast(unsigned short, (__bf16)x);
}
static __device__ __forceinline__ float us2f(unsigned short u){
    return (float)__builtin_bit_cast(__bf16, u);
}
static __device__ __forceinline__ ushort4 cvt4(float4 v){
    ushort4 r; r.x=f2us(v.x); r.y=f2us(v.y); r.z=f2us(v.z); r.w=f2us(v.w); return r;
}
// async global -> LDS, 16B per lane; LDS base must be wave-uniform
static __device__ __forceinline__ void gl16(const void* g, void* l){
    __builtin_amdgcn_global_load_lds(
        (__attribute__((address_space(1))) void*)(g),
        (__attribute__((address_space(3))) void*)(l), 16, 0, 0);
}
template<int N> static __device__ __forceinline__ void wait_vm(){
    asm volatile("s_waitcnt vmcnt(%0)" :: "i"(N) : "memory");
}
static __device__ __forceinline__ void bar(){
    asm volatile("s_barrier" ::: "memory");
}
static __device__ __forceinline__ void bar_lgkm(){
    asm volatile("s_waitcnt lgkmcnt(0)" ::: "memory");
    asm volatile("s_barrier" ::: "memory");
}

// ---------------- routing + top-p gate (+ per-expert counts) ----------------
__global__ __launch_bounds__(256)
void k_route_gate(const float* __restrict__ s, const float* __restrict__ router_w,
                  float* __restrict__ gate_out, int* __restrict__ cnt)
{
    int tok = blockIdx.x;
    int b = tok >> 11, t = tok & (T_-1);
    const float* sbase = s + (size_t)b*NS*TD + (size_t)t*D_;
    __shared__ float rbuf[D_];
    __shared__ float part[16][17];
    __shared__ float logits[16];
    int tid = threadIdx.x;
    for (int dd = tid; dd < D_; dd += 256) {
        float acc = 0.f;
        #pragma unroll
        for (int j=0;j<NS;j++) acc += sbase[(size_t)j*TD + dd];
        rbuf[dd] = acc * 0.25f;
    }
    __syncthreads();
    int e = tid >> 4, m = tid & 15;
    const float* wr = router_w + (size_t)e*D_;
    float acc = 0.f;
    for (int k=m;k<D_;k+=16) acc += rbuf[k]*wr[k];
    part[e][m] = acc;
    __syncthreads();
    if (tid < 16) {
        float sum=0.f;
        for (int q=0;q<16;q++) sum += part[tid][q];
        logits[tid]=sum;
    }
    __syncthreads();
    if (tid==0) {
        float p[16];
        float mx=-1e30f;
        for (int i=0;i<16;i++) mx = fmaxf(mx, logits[i]);
        float sum=0.f;
        for (int i=0;i<16;i++){ p[i]=__expf(logits[i]-mx); sum+=p[i]; }
        float inv=1.0f/sum;
        for (int i=0;i<16;i++) p[i]*=inv;
        float* g = gate_out + (size_t)tok*E_;
        for (int i=0;i<16;i++){
            int rank=0; float csb=0.f;
            for (int k=0;k<16;k++){
                bool before = (p[k]>p[i]) || (p[k]==p[i] && k<i);
                if (before){ rank++; csb+=p[k]; }
            }
            bool msk = (rank==0) || (csb < 0.8f && rank < 4);
            float gv = msk ? p[i] : 0.f;
            g[i] = gv;
            if (gv > 0.f) atomicAdd(&cnt[i], 1);
        }
    }
}

// ---------------- exclusive scan of per-expert counts ----------------
__global__ void k_scan(const int* __restrict__ cnt, int* __restrict__ off)
{
    int o = 0;
    for (int e=0;e<E_;e++){ off[e]=o; o += cnt[e]; }
    off[E_] = o;
}

// ---------------- compacted slot lists ----------------
__global__ __launch_bounds__(256)
void k_fill(const float* __restrict__ gate, const int* __restrict__ off,
            int* __restrict__ cnt2, int* __restrict__ idx, int* __restrict__ eidx,
            int* __restrict__ tokmeta, int* __restrict__ nact)
{
    int tok = blockIdx.x*256 + threadIdx.x;
    if (tok >= BT) return;
    int kk = 0;
    #pragma unroll
    for (int e=0;e<E_;e++){
        float g = gate[(size_t)tok*E_+e];
        if (g > 0.0f){
            int p = atomicAdd(&cnt2[e], 1);
            int s = off[e] + p;
            idx[s] = tok;
            eidx[s] = e;
            tokmeta[tok*4 + kk] = (e<<16) | s;
            kk++;
        }
    }
    nact[tok] = kk;
}

// ---------------- rms over (n*d) fused with scaled bf16 flat copy ----------------
__global__ __launch_bounds__(256)
void k_rmsxb(const float* __restrict__ s, unsigned short* __restrict__ xb)
{
    int tok=blockIdx.x; int b=tok>>11, t=tok&(T_-1);
    const float* sbase = s + (size_t)b*NS*TD + (size_t)t*D_;
    int tid=threadIdx.x;
    float4 v[4]; float ss=0.f;
    #pragma unroll
    for (int j=0;j<4;j++){
        v[j] = *(const float4*)(sbase + (size_t)j*TD + tid*4);
        ss += v[j].x*v[j].x + v[j].y*v[j].y + v[j].z*v[j].z + v[j].w*v[j].w;
    }
    for (int o=32;o>0;o>>=1) ss += __shfl_down(ss,o,64);
    __shared__ float red[4];
    if ((tid&63)==0) red[tid>>6]=ss;
    __syncthreads();
    float sc = rsqrtf((red[0]+red[1]+red[2]+red[3])*(1.0f/ND)+EPS_);
    #pragma unroll
    for (int j=0;j<4;j++){
        float4 a=v[j]; a.x*=sc;a.y*=sc;a.z*=sc;a.w*=sc;
        *(ushort4*)(xb + (size_t)tok*ND + j*1024 + tid*4) = cvt4(a);
    }
}

// ---------------- fold mhc_norm_w * alpha into phi weights -> bf16 ----------------
__global__ __launch_bounds__(256)
void k_fold(const float* __restrict__ pw, const float* __restrict__ ow, const float* __restrict__ rw,
            const float* __restrict__ nw, const float* __restrict__ ap, const float* __restrict__ ao,
            const float* __restrict__ ar, unsigned short* __restrict__ Wallb)
{
    int i = blockIdx.x*256 + threadIdx.x;
    if (i >= E_*24*ND) return;
    int k = i & (ND-1);
    int r = (i >> 12) % 24;
    int e = i / (24*ND);
    float w, a;
    if (r<4)      { w = pw[((size_t)e*4  + r     )*ND + k]; a = ap[e]; }
    else if (r<8) { w = ow[((size_t)e*4  + (r-4) )*ND + k]; a = ao[e]; }
    else          { w = rw[((size_t)e*16 + (r-8) )*ND + k]; a = ar[e]; }
    Wallb[i] = f2us(w * a * nw[(size_t)e*ND + k]);
}

// ---------------- f32 -> bf16 bulk convert ----------------
__global__ __launch_bounds__(256)
void k_cvt(const float* __restrict__ src, unsigned short* __restrict__ dst, size_t n)
{
    size_t i = ((size_t)blockIdx.x*256 + threadIdx.x)*8;
    if (i >= n) return;
    float4 a = *(const float4*)(src+i);
    float4 b = *(const float4*)(src+i+4);
    *(ushort4*)(dst+i)   = cvt4(a);
    *(ushort4*)(dst+i+4) = cvt4(b);
}

// ---------------- down_w f32 [*, 1656] -> bf16 [*, 1664] zero-padded ----------------
__global__ __launch_bounds__(256)
void k_cvt_dw(const float* __restrict__ src, unsigned short* __restrict__ dst)
{
    int r = blockIdx.x; int tid = threadIdx.x;    // 16384 rows
    const float* s = src + (size_t)r*DFFN;
    unsigned short* d = dst + (size_t)r*DFFNP;
    int c = tid*8;
    if (c >= DFFNP) return;
    if (c < DFFN){
        float4 a = *(const float4*)(s+c);
        float4 b = *(const float4*)(s+c+4);
        *(ushort4*)(d+c)   = cvt4(a);
        *(ushort4*)(d+c+4) = cvt4(b);
    } else {
        *(ushort4*)(d+c)   = make_ushort4(0,0,0,0);
        *(ushort4*)(d+c+4) = make_ushort4(0,0,0,0);
    }
}

// ---------------- pre-GEMM split-K, ring-3 pipelined staging ----------------
__global__ __launch_bounds__(256)
void k_mm_pre(const unsigned short* __restrict__ A, const unsigned short* __restrict__ Wb,
              float* __restrict__ C)
{
    const int n0 = blockIdx.x*128;
    const int m0 = blockIdx.y*128;
    const int kz = blockIdx.z;

    __shared__ unsigned short As[3*128*32];
    __shared__ unsigned short Ws[3*128*32];

    const int tid = threadIdx.x;
    const int lane = tid & 63, w = tid >> 6;
    const int wm = (w>>1)*64, wn = (w&1)*64;
    const int lr = lane & 15, kg = lane >> 4;
    const int srow = lane >> 2, sk = (lane & 3)*8;

    int aoff[4], boff[4];
    #pragma unroll
    for (int i=0;i<4;i++){ aoff[i] = (wm+i*16+lr)*32 + kg*8; boff[i] = (wn+i*16+lr)*32 + kg*8; }

    const unsigned short* pA0 = &A[(size_t)(m0 + w*16     + srow)*ND + sk];
    const unsigned short* pA1 = &A[(size_t)(m0 + (w+4)*16 + srow)*ND + sk];
    const unsigned short* pW0 = &Wb[(size_t)(n0 + w*16     + srow)*ND + sk];
    const unsigned short* pW1 = &Wb[(size_t)(n0 + (w+4)*16 + srow)*ND + sk];
    const int lds0 = w*512, lds1 = (w+4)*512;

#define STG_P(buf, k0) do{ \
    gl16(pA0 + (k0), &As[(buf)*4096 + lds0]); \
    gl16(pW0 + (k0), &Ws[(buf)*4096 + lds0]); \
    gl16(pA1 + (k0), &As[(buf)*4096 + lds1]); \
    gl16(pW1 + (k0), &Ws[(buf)*4096 + lds1]); \
}while(0)

    f32x4 acc[4][4] = {};
    const int kbeg = kz*(ND/KSPLIT);
    const int nt = (ND/KSPLIT)/32;          // 8

    STG_P(0, kbeg);
    STG_P(1, kbeg+32);
    int cur=0, nxt=1, pre=2;
    for (int t=0; t<nt; ++t){
        if (t+2 < nt){ STG_P(pre, kbeg+(t+2)*32); wait_vm<8>(); }
        else if (t+1 < nt){ wait_vm<4>(); }
        else { wait_vm<0>(); }
        bar();
        const unsigned short* Ab = &As[cur*4096];
        const unsigned short* Wc = &Ws[cur*4096];
        bf16x8 af[4], bw[4];
        #pragma unroll
        for (int i=0;i<4;i++) af[i] = *(const bf16x8*)(const void*)&Ab[aoff[i]];
        #pragma unroll
        for (int j=0;j<4;j++) bw[j] = *(const bf16x8*)(const void*)&Wc[boff[j]];
        #pragma unroll
        for (int i=0;i<4;i++)
            #pragma unroll
            for (int j=0;j<4;j++)
                acc[i][j] = __builtin_amdgcn_mfma_f32_16x16x32_bf16(af[i], bw[j], acc[i][j], 0,0,0);
        bar_lgkm();
        int tmp=cur; cur=nxt; nxt=pre; pre=tmp;
    }
#undef STG_P

    #pragma unroll
    for (int i=0;i<4;i++){
        #pragma unroll
        for (int r=0;r<4;r++){
            int gr = m0 + wm + i*16 + kg*4 + r;
            #pragma unroll
            for (int j=0;j<4;j++){
                int gc = n0 + wn + j*16 + lr;
                if (gc >= 384) continue;
                atomicAdd(&C[(size_t)gr*384 + gc], acc[i][j][r]);
            }
        }
    }
}

// ---------------- activations + sinkhorn ----------------
__global__ __launch_bounds__(256)
void k_act(const float* __restrict__ preact, const float* __restrict__ b_pre,
           const float* __restrict__ b_post, const float* __restrict__ b_res,
           float* __restrict__ Hpre, float* __restrict__ Hpost, float* __restrict__ Hres)
{
    int i = blockIdx.x*256 + threadIdx.x;
    int tok = i & (BT-1);
    int e = i >> 12;
    const float* pr = preact + (size_t)tok*384 + e*24;
    float* hp = Hpre  + ((size_t)e*BT+tok)*4;
    float* ho = Hpost + ((size_t)e*BT+tok)*4;
    float* hr = Hres  + ((size_t)e*BT+tok)*16;
    #pragma unroll
    for (int r=0;r<4;r++) hp[r] = sigm(pr[r] + b_pre[e*4+r]);
    #pragma unroll
    for (int r=0;r<4;r++) ho[r] = 2.0f*sigm(pr[4+r] + b_post[e*4+r]);
    float Mv[16];
    #pragma unroll
    for (int r=0;r<16;r++) Mv[r] = __expf(pr[8+r] + b_res[e*16+r]);
    #pragma unroll
    for (int it=0; it<6; it++){
        #pragma unroll
        for (int r=0;r<4;r++){
            float inv = 1.0f/(Mv[4*r]+Mv[4*r+1]+Mv[4*r+2]+Mv[4*r+3]);
            Mv[4*r]*=inv; Mv[4*r+1]*=inv; Mv[4*r+2]*=inv; Mv[4*r+3]*=inv;
        }
        #pragma unroll
        for (int c=0;c<4;c++){
            float inv = 1.0f/(Mv[c]+Mv[4+c]+Mv[8+c]+Mv[12+c]);
            Mv[c]*=inv; Mv[4+c]*=inv; Mv[8+c]*=inv; Mv[12+c]*=inv;
        }
    }
    #pragma unroll
    for (int r=0;r<16;r++) hr[r]=Mv[r];
}

// ---------------- h = sum_j Hpre_j*stream_j ; hn = rms(h)*snw -> bf16 ----------------
__global__ __launch_bounds__(256)
void k_hn_all(const float* __restrict__ s, const float* __restrict__ Hpre,
              const float* __restrict__ snw, const int* __restrict__ off,
              const int* __restrict__ idx, const int* __restrict__ eidx,
              unsigned short* __restrict__ hn)
{
    int sl = blockIdx.x;
    if (sl >= off[E_]) return;
    int e = eidx[sl], tok = idx[sl];
    int b=tok>>11, t=tok&2047;
    const float* sbase = s + (size_t)b*NS*TD + (size_t)t*D_;
    const float* hp = Hpre + ((size_t)e*BT+tok)*4;
    float h0=hp[0], h1=hp[1], h2=hp[2], h3=hp[3];
    int tid=threadIdx.x;
    float hv[4]; float ss=0.f;
    #pragma unroll
    for (int u=0;u<4;u++){
        int dd = tid + u*256;
        float v = h0*sbase[dd] + h1*sbase[(size_t)TD+dd]
                + h2*sbase[(size_t)2*TD+dd] + h3*sbase[(size_t)3*TD+dd];
        hv[u]=v; ss += v*v;
    }
    for (int o=32;o>0;o>>=1) ss += __shfl_down(ss, o, 64);
    __shared__ float red[4];
    if ((tid&63)==0) red[tid>>6]=ss;
    __syncthreads();
    float tot = red[0]+red[1]+red[2]+red[3];
    float scale = rsqrtf(tot*(1.0f/D_) + EPS_);
    const float* sw = snw + (size_t)e*D_;
    #pragma unroll
    for (int u=0;u<4;u++){
        int dd = tid + u*256;
        hn[(size_t)sl*D_+dd] = f2us(hv[u]*scale*sw[dd]);
    }
}

// =====================================================================
// batched bf16 GEMM over experts; ring-3 counted-vmcnt pipeline
// EPI: 1 = silu ; 2 = sigmoid ; 3 = * aux(bf16)
// =====================================================================
template<int EPI>
__global__ __launch_bounds__(256)
void k_mm(const unsigned short* __restrict__ A, const unsigned short* __restrict__ Wb,
          unsigned short* __restrict__ C, const unsigned short* __restrict__ aux,
          const int* __restrict__ cnt, const int* __restrict__ off,
          int N, int K, int ldc, size_t wstride)
{
    const int e = blockIdx.z;
    const int Mact = cnt[e];
    const int m0 = blockIdx.y*128;
    if (m0 >= Mact) return;
    const int n0 = blockIdx.x*128;
    const size_t rb = off[e];
    const unsigned short* W = Wb + (size_t)e*wstride;

    __shared__ unsigned short As[3*128*32];
    __shared__ unsigned short Ws[3*128*32];

    const int tid = threadIdx.x;
    const int lane = tid & 63, w = tid >> 6;
    const int wm = (w>>1)*64, wn = (w&1)*64;
    const int lr = lane & 15, kg = lane >> 4;
    const int srow = lane >> 2, sk = (lane & 3)*8;

    int aoff[4], boff[4];
    #pragma unroll
    for (int i=0;i<4;i++){ aoff[i] = (wm+i*16+lr)*32 + kg*8; boff[i] = (wn+i*16+lr)*32 + kg*8; }

    int rA0 = m0 + w*16 + srow;     if (rA0 >= Mact) rA0 = Mact-1;
    int rA1 = m0 + (w+4)*16 + srow; if (rA1 >= Mact) rA1 = Mact-1;
    int rW0 = n0 + w*16 + srow;     if (rW0 >= N)    rW0 = N-1;
    int rW1 = n0 + (w+4)*16 + srow; if (rW1 >= N)    rW1 = N-1;
    const unsigned short* pA0 = &A[(rb+rA0)*(size_t)K + sk];
    const unsigned short* pA1 = &A[(rb+rA1)*(size_t)K + sk];
    const unsigned short* pW0 = &W[(size_t)rW0*K + sk];
    const unsigned short* pW1 = &W[(size_t)rW1*K + sk];
    const int lds0 = w*512, lds1 = (w+4)*512;

#define STG_M(buf, k0) do{ \
    gl16(pA0 + (k0), &As[(buf)*4096 + lds0]); \
    gl16(pW0 + (k0), &Ws[(buf)*4096 + lds0]); \
    gl16(pA1 + (k0), &As[(buf)*4096 + lds1]); \
    gl16(pW1 + (k0), &Ws[(buf)*4096 + lds1]); \
}while(0)

    f32x4 acc[4][4] = {};
    const int nt = K/32;

    STG_M(0, 0);
    STG_M(1, 32);
    int cur=0, nxt=1, pre=2;
    for (int t=0; t<nt; ++t){
        if (t+2 < nt){ STG_M(pre, (t+2)*32); wait_vm<8>(); }
        else if (t+1 < nt){ wait_vm<4>(); }
        else { wait_vm<0>(); }
        bar();
        const unsigned short* Ab = &As[cur*4096];
        const unsigned short* Wc = &Ws[cur*4096];
        bf16x8 af[4], bw[4];
        #pragma unroll
        for (int i=0;i<4;i++) af[i] = *(const bf16x8*)(const void*)&Ab[aoff[i]];
        #pragma unroll
        for (int j=0;j<4;j++) bw[j] = *(const bf16x8*)(const void*)&Wc[boff[j]];
        #pragma unroll
        for (int i=0;i<4;i++)
            #pragma unroll
            for (int j=0;j<4;j++)
                acc[i][j] = __builtin_amdgcn_mfma_f32_16x16x32_bf16(af[i], bw[j], acc[i][j], 0,0,0);
        bar_lgkm();
        int tmp=cur; cur=nxt; nxt=pre; pre=tmp;
    }
#undef STG_M

    #pragma unroll
    for (int i=0;i<4;i++){
        #pragma unroll
        for (int r=0;r<4;r++){
            int gr = m0 + wm + i*16 + kg*4 + r;
            if (gr >= Mact) continue;
            #pragma unroll
            for (int j=0;j<4;j++){
                int gc = n0 + wn + j*16 + lr;
                if (gc >= N) continue;
                float v = acc[i][j][r];
                if (EPI==1)      v = v*sigm(v);
                else if (EPI==2) v = sigm(v);
                else             v = v*us2f(aux[(rb+gr)*(size_t)ldc + gc]);
                C[(rb+gr)*(size_t)ldc + gc] = f2us(v);
            }
        }
    }
}

// ---------------- fused gate+up GEMM, ring-2 pipeline (LDS budget) ----------------
__global__ __launch_bounds__(256)
void k_mm_gateup(const unsigned short* __restrict__ A, const unsigned short* __restrict__ GWb,
                 const unsigned short* __restrict__ UWb, unsigned short* __restrict__ P,
                 const int* __restrict__ cnt, const int* __restrict__ off)
{
    const int e = blockIdx.z;
    const int Mact = cnt[e];
    const int m0 = blockIdx.y*128;
    if (m0 >= Mact) return;
    const int n0 = blockIdx.x*128;
    const size_t rb = off[e];
    const unsigned short* GW = GWb + (size_t)e*DFFN*D_;
    const unsigned short* UW = UWb + (size_t)e*DFFN*D_;

    __shared__ unsigned short As[2*128*32];
    __shared__ unsigned short Gs[2*128*32];
    __shared__ unsigned short Us[2*128*32];

    const int tid = threadIdx.x;
    const int lane = tid & 63, w = tid >> 6;
    const int wm = (w>>1)*64, wn = (w&1)*64;
    const int lr = lane & 15, kg = lane >> 4;
    const int srow = lane >> 2, sk = (lane & 3)*8;

    int aoff[4], boff[4];
    #pragma unroll
    for (int i=0;i<4;i++){ aoff[i] = (wm+i*16+lr)*32 + kg*8; boff[i] = (wn+i*16+lr)*32 + kg*8; }

    int rA0 = m0 + w*16 + srow;     if (rA0 >= Mact) rA0 = Mact-1;
    int rA1 = m0 + (w+4)*16 + srow; if (rA1 >= Mact) rA1 = Mact-1;
    int rW0 = n0 + w*16 + srow;     if (rW0 >= DFFN) rW0 = DFFN-1;
    int rW1 = n0 + (w+4)*16 + srow; if (rW1 >= DFFN) rW1 = DFFN-1;
    const unsigned short* pA0 = &A[(rb+rA0)*(size_t)D_ + sk];
    const unsigned short* pA1 = &A[(rb+rA1)*(size_t)D_ + sk];
    const unsigned short* pG0 = &GW[(size_t)rW0*D_ + sk];
    const unsigned short* pG1 = &GW[(size_t)rW1*D_ + sk];
    const unsigned short* pU0 = &UW[(size_t)rW0*D_ + sk];
    const unsigned short* pU1 = &UW[(size_t)rW1*D_ + sk];
    const int lds0 = w*512, lds1 = (w+4)*512;

#define STG_G(buf, k0) do{ \
    gl16(pA0 + (k0), &As[(buf)*4096 + lds0]); \
    gl16(pG0 + (k0), &Gs[(buf)*4096 + lds0]); \
    gl16(pU0 + (k0), &Us[(buf)*4096 + lds0]); \
    gl16(pA1 + (k0), &As[(buf)*4096 + lds1]); \
    gl16(pG1 + (k0), &Gs[(buf)*4096 + lds1]); \
    gl16(pU1 + (k0), &Us[(buf)*4096 + lds1]); \
}while(0)

    f32x4 accg[4][4] = {};
    f32x4 accu[4][4] = {};
    const int nt = D_/32;   // 32

    STG_G(0, 0);
    for (int t=0; t<nt; ++t){
        if (t+1 < nt){ STG_G((t+1)&1, (t+1)*32); wait_vm<6>(); }
        else { wait_vm<0>(); }
        bar();
        const int bb = (t&1)*4096;
        bf16x8 af[4], bg[4], bu[4];
        #pragma unroll
        for (int i=0;i<4;i++) af[i] = *(const bf16x8*)(const void*)&As[bb+aoff[i]];
        #pragma unroll
        for (int j=0;j<4;j++) bg[j] = *(const bf16x8*)(const void*)&Gs[bb+boff[j]];
        #pragma unroll
        for (int j=0;j<4;j++) bu[j] = *(const bf16x8*)(const void*)&Us[bb+boff[j]];
        #pragma unroll
        for (int i=0;i<4;i++){
            #pragma unroll
            for (int j=0;j<4;j++){
                accg[i][j] = __builtin_amdgcn_mfma_f32_16x16x32_bf16(af[i], bg[j], accg[i][j], 0,0,0);
                accu[i][j] = __builtin_amdgcn_mfma_f32_16x16x32_bf16(af[i], bu[j], accu[i][j], 0,0,0);
            }
        }
        bar_lgkm();
    }
#undef STG_G

    #pragma unroll
    for (int i=0;i<4;i++){
        #pragma unroll
        for (int r=0;r<4;r++){
            int gr = m0 + wm + i*16 + kg*4 + r;
            if (gr >= Mact) continue;
            #pragma unroll
            for (int j=0;j<4;j++){
                int gc = n0 + wn + j*16 + lr;   // < 1664 always (13*128 grid)
                float g = accg[i][j][r];
                float u = accu[i][j][r];
                P[(rb+gr)*(size_t)DFFNP + gc] = (gc < DFFN) ? f2us(g*sigm(g)*u)
                                                            : (unsigned short)0;
            }
        }
    }
}

// ---------------- final: out[tok] = sum_e g*(Hres@stream + Hpost*outc) ----------------
__global__ __launch_bounds__(256)
void k_accum_all(const float* __restrict__ s, const float* __restrict__ gate,
                 const float* __restrict__ Hres, const float* __restrict__ Hpost,
                 const unsigned short* __restrict__ outc, const int* __restrict__ tokmeta,
                 const int* __restrict__ nact, float* __restrict__ outp)
{
    int tok = blockIdx.x;
    int b=tok>>11, t=tok&2047;
    int na = nact[tok];
    __shared__ float sR[4][16];
    __shared__ float sP[4][4];
    __shared__ float sg[4];
    __shared__ int ssl[4];
    int tid = threadIdx.x;
    if (tid < 64){
        int k = tid >> 4, r = tid & 15;
        if (k < na){
            int meta = tokmeta[tok*4 + k];
            int e = meta >> 16;
            sR[k][r] = Hres[((size_t)e*BT+tok)*16 + r];
            if (r < 4) sP[k][r] = Hpost[((size_t)e*BT+tok)*4 + r];
            if (r == 0){
                sg[k] = gate[(size_t)tok*E_ + e];
                ssl[k] = meta & 0xffff;
            }
        }
    }
    __syncthreads();
    const float* sbase = s    + (size_t)b*NS*TD + (size_t)t*D_;
    float* obase       = outp + (size_t)b*NS*TD + (size_t)t*D_;
    #pragma unroll
    for (int u=0;u<4;u++){
        int dd = tid + u*256;
        float s0=sbase[dd], s1=sbase[(size_t)TD+dd], s2=sbase[(size_t)2*TD+dd], s3=sbase[(size_t)3*TD+dd];
        float a0=0.f, a1=0.f, a2=0.f, a3=0.f;
        for (int k=0;k<na;k++){
            float g = sg[k];
            float ov = us2f(outc[(size_t)ssl[k]*D_ + dd]);
            a0 += g*(sR[k][0] *s0 + sR[k][1] *s1 + sR[k][2] *s2 + sR[k][3] *s3 + sP[k][0]*ov);
            a1 += g*(sR[k][4] *s0 + sR[k][5] *s1 + sR[k][6] *s2 + sR[k][7] *s3 + sP[k][1]*ov);
            a2 += g*(sR[k][8] *s0 + sR[k][9] *s1 + sR[k][10]*s2 + sR[k][11]*s3 + sP[k][2]*ov);
            a3 += g*(sR[k][12]*s0 + sR[k][13]*s1 + sR[k][14]*s2 + sR[k][15]*s3 + sP[k][3]*ov);
        }
        obase[dd]               = a0;
        obase[(size_t)TD+dd]    = a1;
        obase[(size_t)2*TD+dd]  = a2;
        obase[(size_t)3*TD+dd]  = a3;
    }
}

extern "C" void kernel_launch(void* const* d_in, const int* in_sizes, int n_in,
                              void* d_out, int out_size, void* d_ws, size_t ws_size,
                              hipStream_t stream)
{
    const float* s_in       = (const float*)d_in[0];
    const float* router_w   = (const float*)d_in[1];
    const float* mhc_norm_w = (const float*)d_in[2];
    const float* phi_pre_w  = (const float*)d_in[3];
    const float* phi_post_w = (const float*)d_in[4];
    const float* phi_res_w  = (const float*)d_in[5];
    const float* b_pre      = (const float*)d_in[6];
    const float* b_post     = (const float*)d_in[7];
    const float* b_res      = (const float*)d_in[8];
    const float* alpha_pre  = (const float*)d_in[9];
    const float* alpha_post = (const float*)d_in[10];
    const float* alpha_res  = (const float*)d_in[11];
    const float* sw_norm_w  = (const float*)d_in[12];
    const float* wd_w       = (const float*)d_in[13];
    const float* wu_w       = (const float*)d_in[14];
    const float* gate_w     = (const float*)d_in[15];
    const float* up_w       = (const float*)d_in[16];
    const float* down_w     = (const float*)d_in[17];

    float* out_stream = (float*)d_out;
    float* gate_out   = out_stream + (size_t)B_*NS*T_*D_;

    char* w = (char*)d_ws;
    int* cnt   = (int*)w;        // [16]
    int* cnt2  = cnt + 16;       // [16]
    int* off   = cnt + 32;       // [17]
    w += 256;
    int* idx     = (int*)w; w += (size_t)RCAP*4;
    int* eidx    = (int*)w; w += (size_t)RCAP*4;
    int* tokmeta = (int*)w; w += (size_t)BT*4*4;
    int* nact    = (int*)w; w += (size_t)BT*4;
    unsigned short* Wallb = (unsigned short*)w; w += (size_t)E_*24*ND*2;
    float* preact  = (float*)w; w += (size_t)BT*384*4;
    float* Hpre    = (float*)w; w += (size_t)E_*BT*4*4;
    float* Hpost   = (float*)w; w += (size_t)E_*BT*4*4;
    float* Hres    = (float*)w; w += (size_t)E_*BT*16*4;
    unsigned short* hn   = (unsigned short*)w; w += (size_t)(RCAP+128)*D_*2;
    unsigned short* Abuf = (unsigned short*)w; w += (size_t)(RCAP+128)*D_*2;
    unsigned short* Pbuf = (unsigned short*)w; w += (size_t)(RCAP+128)*DFFNP*2;
    unsigned short* scr  = (unsigned short*)w; w += (size_t)(E_*DFFN*D_*2 + E_*D_*DFFNP)*2;

    unsigned short* xb   = Abuf;                 // dead after k_mm_pre; Abuf used later
    unsigned short* gsig = hn;                   // hn dead after gateup + wd
    unsigned short* outc = Abuf;                 // Abuf dead after wu
    unsigned short* gwb  = scr;                                   // phase 1
    unsigned short* uwb  = scr + (size_t)E_*DFFN*D_;
    unsigned short* wdb  = scr;                                   // phase 2
    unsigned short* wub  = scr + (size_t)E_*D_*D_;
    unsigned short* dwb  = scr + (size_t)2*E_*D_*D_;

    hipMemsetAsync(cnt, 0, 256, stream);
    hipMemsetAsync(preact, 0, (size_t)BT*384*4, stream);

    k_route_gate<<<BT,256,0,stream>>>(s_in, router_w, gate_out, cnt);
    k_scan<<<1,1,0,stream>>>(cnt, off);
    k_fill<<<BT/256,256,0,stream>>>(gate_out, off, cnt2, idx, eidx, tokmeta, nact);
    k_rmsxb<<<BT,256,0,stream>>>(s_in, xb);
    {
        int tot = E_*24*ND;
        k_fold<<<(tot+255)/256,256,0,stream>>>(phi_pre_w, phi_post_w, phi_res_w,
                                               mhc_norm_w, alpha_pre, alpha_post, alpha_res, Wallb);
    }
    {   // phase-1 weight converts (gate, up)
        size_t n = (size_t)E_*DFFN*D_;
        k_cvt<<<(unsigned)(n/2048),256,0,stream>>>(gate_w, gwb, n);
        k_cvt<<<(unsigned)(n/2048),256,0,stream>>>(up_w,   uwb, n);
    }
    k_mm_pre<<<dim3(3, BT/128, KSPLIT),256,0,stream>>>(xb, Wallb, preact);
    k_act<<<(BT*E_)/256,256,0,stream>>>(preact, b_pre, b_post, b_res, Hpre, Hpost, Hres);
    k_hn_all<<<RCAP,256,0,stream>>>(s_in, Hpre, sw_norm_w, off, idx, eidx, hn);

    const int MT   = BT/128;            // 32 m-tiles (early-exit past cnt)
    const int NT_D = D_/128;            // 8
    const int NT_F = DFFNP/128;         // 13

    // gate+up fused -> Pbuf
    k_mm_gateup<<<dim3(NT_F,MT,E_),256,0,stream>>>(hn, gwb, uwb, Pbuf, cnt, off);

    {   // phase-2 weight converts (wd, wu, down) -- reuse scratch after gateup
        size_t n = (size_t)E_*D_*D_;
        k_cvt<<<(unsigned)(n/2048),256,0,stream>>>(wd_w, wdb, n);
        k_cvt<<<(unsigned)(n/2048),256,0,stream>>>(wu_w, wub, n);
        k_cvt_dw<<<E_*D_,256,0,stream>>>(down_w, dwb);
    }
    // wd: Abuf = silu(hn @ wd^T)
    k_mm<1><<<dim3(NT_D,MT,E_),256,0,stream>>>(
        hn, wdb, Abuf, nullptr, cnt, off, D_, D_, D_, (size_t)D_*D_);
    // wu: gsig(=hn) = sigmoid(Abuf @ wu^T)
    k_mm<2><<<dim3(NT_D,MT,E_),256,0,stream>>>(
        Abuf, wub, gsig, nullptr, cnt, off, D_, D_, D_, (size_t)D_*D_);
    // down: outc(=Abuf) = gsig * (Pbuf @ down^T)
    k_mm<3><<<dim3(NT_D,MT,E_),256,0,stream>>>(
        Pbuf, dwb, outc, gsig, cnt, off, D_, DFFNP, D_, (size_t)D_*DFFNP);
    k_accum_all<<<BT,256,0,stream>>>(s_in, gate_out, Hres, Hpost, outc, tokmeta, nact, out_stream);
}